// Round 8
// baseline (39.478 us; speedup 1.0000x reference)
//
#include <hip/hip_runtime.h>
#include <hip/hip_fp16.h>

// B=32, L=512, N=128, IN=16, OUT=10
// Two kernels, one boundary:
//  K1 k_micro: h16 = (half)relu(relu(x@W1+b1)@W2+b2)  (B*L, 64) packed f16.
//              block 0 also zeroes the arrival counter.
//  K2 k_agg_part: per (ng=8 nodes, b): bitmask max-agg on packed f16 pairs
//              (bfe+and+pk_max = 3 VALU per 2 channels), fused f_macro +
//              W4 slice -> part[b][16][64]; LAST block (atomic counter)
//              does combine + BatchNorm (batch stats) + @W5+b5 -> out.

// ROCm 7.2 headers lack a gfx950-viable __hmax2; emit the instruction directly.
static __device__ __forceinline__ unsigned pk_max_f16(unsigned a, unsigned b) {
    unsigned r;
    asm("v_pk_max_f16 %0, %1, %2" : "=v"(r) : "v"(a), "v"(b));
    return r;
}

__global__ __launch_bounds__(256) void k_micro(
    const float* __restrict__ x, const float* __restrict__ W1,
    const float* __restrict__ b1, const float* __restrict__ W2,
    const float* __restrict__ b2, unsigned* __restrict__ h16,
    unsigned* __restrict__ counter)
{
    const int tid = threadIdx.x;
    const int r = tid >> 5;                 // row within block (0..7)
    const int p = tid & 31;                 // channel pair (ch 2p, 2p+1)
    const int row0 = blockIdx.x * 8;

    if (blockIdx.x == 0 && tid == 0) *counter = 0u;   // reset arrival counter

    __shared__ float sx[8][16];
    __shared__ float sh1[8][32];

    if (tid < 128) sx[tid >> 4][tid & 15] = x[(size_t)row0 * 16 + tid];

    // preload W2 column pair into registers (32 x float2)
    float2 w2[32];
    #pragma unroll
    for (int j = 0; j < 32; ++j) w2[j] = *(const float2*)&W2[j * 64 + 2 * p];
    const float2 b2p = *(const float2*)&b2[2 * p];
    __syncthreads();

    {   // layer1: 256 thr = 8 rows x 32 cols
        const int rr = tid >> 5, c = tid & 31;
        float a = b1[c];
        #pragma unroll
        for (int i = 0; i < 16; ++i) a += sx[rr][i] * W1[i * 32 + c];
        sh1[rr][c] = fmaxf(a, 0.f);
    }
    __syncthreads();

    {   // layer2: each thread computes 2 channels, packs to f16x2
        float a0 = b2p.x, a1 = b2p.y;
        #pragma unroll
        for (int j = 0; j < 32; ++j) {
            float v = sh1[r][j];
            a0 += v * w2[j].x;
            a1 += v * w2[j].y;
        }
        __half2 hp = __floats2half2_rn(fmaxf(a0, 0.f), fmaxf(a1, 0.f));
        h16[(size_t)(row0 + r) * 32 + p] = *(unsigned*)&hp;
    }
}

// grid 512 (XCD-swizzled), 512 threads = 8 waves.
__global__ __launch_bounds__(512, 4) void k_agg_part(
    const unsigned* __restrict__ h16,  // [B][512][32] f16x2
    const float* __restrict__ tree,    // [128][512]
    const float* __restrict__ W3, const float* __restrict__ b3,
    const float* __restrict__ W4, const float* __restrict__ b4,
    const float* __restrict__ gamma, const float* __restrict__ beta,
    const float* __restrict__ W5, const float* __restrict__ b5,
    float* __restrict__ part, unsigned* __restrict__ counter,
    float* __restrict__ out)
{
    const int id   = blockIdx.x;          // 0..511
    const int b    = (id & 7) * 4 + ((id >> 3) & 3);
    const int ng   = id >> 5;             // 0..15 (nodes ng*8 .. ng*8+7)
    const int tid  = threadIdx.x;
    const int w    = tid >> 6;            // wave 0..7
    const int lane = tid & 63;
    const int half = lane >> 5;           // which of 2 leaves per iter
    const int p    = lane & 31;           // channel pair

    __shared__ unsigned smask[512];       // per-leaf 8-bit node mask
    __shared__ float sred[8][8][64];      // cross-wave max reduce
    __shared__ float sagg[8][64];
    __shared__ float sm[128];
    __shared__ float spart[8][64];
    __shared__ int slast;
    __shared__ float sy[2048];
    __shared__ float sstat[3][64];

    // ---- per-leaf masks (thread owns leaf tid; coalesced; no atomics) ----
    {
        unsigned bits = 0;
        const float* tp = tree + (size_t)(ng * 8) * 512 + tid;
        #pragma unroll
        for (int n = 0; n < 8; ++n)
            if (tp[(size_t)n * 512] > 0.5f) bits |= (1u << n);
        smask[tid] = bits;
    }
    __syncthreads();

    // ---- packed max-aggregation: wave w owns leaves w*64..w*64+63 ----
    unsigned acc[8];
    #pragma unroll
    for (int n = 0; n < 8; ++n) acc[n] = 0u;        // +0,+0 in f16; h>=0 exact

    const unsigned* hb = h16 + (size_t)b * 16384 + (size_t)(w * 64 + half) * 32 + p;
    const unsigned* mp = &smask[w * 64 + half];
    #pragma unroll 8
    for (int j = 0; j < 32; ++j) {
        unsigned hv  = hb[(size_t)(2 * j) * 32];    // 2 f16 ch, coalesced
        unsigned msk = mp[2 * j];                   // LDS broadcast (2 addr)
        #pragma unroll
        for (int n = 0; n < 8; ++n) {
            int sel = (int)(msk << (31 - n)) >> 31; // bfe: 0 / ~0
            acc[n] = pk_max_f16(acc[n], hv & (unsigned)sel);
        }
    }
    // combine the two half-wave leaf groups
    #pragma unroll
    for (int n = 0; n < 8; ++n) {
        int bi = __shfl_xor((int)acc[n], 32);
        acc[n] = pk_max_f16(acc[n], (unsigned)bi);
    }
    if (half == 0) {
        #pragma unroll
        for (int n = 0; n < 8; ++n) {
            __half2 hh = *(__half2*)&acc[n];
            float2 v = make_float2(__low2float(hh), __high2float(hh));
            *(float2*)&sred[w][n][2 * p] = v;
        }
    }
    __syncthreads();

    {   // combine 8 waves: tid covers (n=tid>>6, c=tid&63)
        const int n = tid >> 6, c = tid & 63;
        float v = sred[0][n][c];
        #pragma unroll
        for (int ww = 1; ww < 8; ++ww) v = fmaxf(v, sred[ww][n][c]);
        sagg[n][c] = v;
    }
    __syncthreads();

    // ---- f_macro: m[n][jj] = relu(b3 + sum_c h_agg*W3) ----
    if (tid < 128) {
        int n = tid >> 4, jj = tid & 15;
        float a = b3[jj];
        #pragma unroll
        for (int c2 = 0; c2 < 64; ++c2)
            a += sagg[n][c2] * W3[c2 * 16 + jj];
        sm[tid] = fmaxf(a, 0.f);
    }
    __syncthreads();

    // ---- W4 slice: part[b][ng][o] = sum_{k in ng*128..+128} m[k]*W4[k][o]
    {
        float a = 0.f;
        const float* w4p = W4 + (size_t)(ng * 128 + w * 16) * 64 + lane;
        #pragma unroll
        for (int k2 = 0; k2 < 16; ++k2)
            a += sm[w * 16 + k2] * w4p[(size_t)k2 * 64];
        spart[w][lane] = a;
    }
    __syncthreads();
    if (tid < 64) {
        float v = 0.f;
        #pragma unroll
        for (int ww = 0; ww < 8; ++ww) v += spart[ww][tid];
        part[((size_t)b * 16 + ng) * 64 + tid] = v;
    }
    __syncthreads();

    // ---- arrival: last block does combine + BN + final linear ----
    if (tid == 0) {
        __threadfence();                               // flush part to device
        unsigned old = atomicAdd(counter, 1u);
        slast = (old == 511u);
    }
    __syncthreads();
    if (!slast) return;

    __threadfence();
    #pragma unroll
    for (int idx = tid; idx < 2048; idx += 512) {
        int bb = idx >> 6, o = idx & 63;
        float v = b4[o];
        #pragma unroll
        for (int s = 0; s < 16; ++s)
            v += __hip_atomic_load(&part[((size_t)bb * 16 + s) * 64 + o],
                                   __ATOMIC_RELAXED, __HIP_MEMORY_SCOPE_AGENT);
        sy[idx] = fmaxf(v, 0.f);
    }
    __syncthreads();
    if (tid < 64) {
        float s1 = 0.f, s2 = 0.f;
        #pragma unroll
        for (int bb = 0; bb < 32; ++bb) {
            float v = sy[bb * 64 + tid];
            s1 += v; s2 += v * v;
        }
        float mean = s1 * (1.f / 32.f);
        float var  = s2 * (1.f / 32.f) - mean * mean;   // biased, torch BN
        sstat[0][tid] = mean;
        sstat[1][tid] = gamma[tid] * rsqrtf(var + 1e-5f);
        sstat[2][tid] = beta[tid];
    }
    __syncthreads();
    if (tid < 320) {
        int bb = tid / 10, q = tid % 10;
        float a = b5[q];
        #pragma unroll
        for (int o = 0; o < 64; ++o)
            a += ((sy[bb * 64 + o] - sstat[0][o]) * sstat[1][o] + sstat[2][o])
                 * W5[o * 10 + q];
        out[bb * 10 + q] = a;
    }
}

extern "C" void kernel_launch(void* const* d_in, const int* in_sizes, int n_in,
                              void* d_out, int out_size, void* d_ws, size_t ws_size,
                              hipStream_t stream) {
    const float* x     = (const float*)d_in[0];
    const float* tree  = (const float*)d_in[1];
    const float* W1    = (const float*)d_in[2];
    const float* b1    = (const float*)d_in[3];
    const float* W2    = (const float*)d_in[4];
    const float* b2    = (const float*)d_in[5];
    const float* W3    = (const float*)d_in[6];
    const float* b3    = (const float*)d_in[7];
    const float* W4    = (const float*)d_in[8];
    const float* b4    = (const float*)d_in[9];
    const float* gamma = (const float*)d_in[10];
    const float* beta  = (const float*)d_in[11];
    const float* W5    = (const float*)d_in[12];
    const float* b5    = (const float*)d_in[13];
    float* out = (float*)d_out;

    unsigned* h16     = (unsigned*)d_ws;            // 16384*32 u32 = 2 MB
    float*    part    = (float*)(h16 + 16384 * 32); // 32*16*64 f32 = 128 KB
    unsigned* counter = (unsigned*)(part + 32 * 16 * 64);

    k_micro   <<<2048, 256, 0, stream>>>(x, W1, b1, W2, b2, h16, counter);
    k_agg_part<<<512,  512, 0, stream>>>(h16, tree, W3, b3, W4, b4,
                                         gamma, beta, W5, b5,
                                         part, counter, out);
}

// Round 9
// 29.845 us; speedup vs baseline: 1.3228x; 1.3228x over previous
//
#include <hip/hip_runtime.h>
#include <hip/hip_fp16.h>

// B=32, L=512, N=128, IN=16, OUT=10
// Three kernels (R6 structure, proven fence-free), f16-packed aggregation:
//  K1 k_micro   : h16 = (half2)relu(relu(x@W1+b1)@W2+b2)   (B*L, 32 pairs)
//  K2 k_agg_part: per (ng=8 nodes, b): bitmask max-agg on f16 pairs
//                 (bfe+and+pk_max = 3 VALU / 2 channels), fused f_macro +
//                 W4 slice -> part[b][16][64]
//  K3 k_bn_out  : y = relu(sum part + b4); BatchNorm (batch stats); @W5+b5

// ROCm 7.2 headers lack a gfx950-viable __hmax2; emit the instruction directly.
static __device__ __forceinline__ unsigned pk_max_f16(unsigned a, unsigned b) {
    unsigned r;
    asm("v_pk_max_f16 %0, %1, %2" : "=v"(r) : "v"(a), "v"(b));
    return r;
}

__global__ __launch_bounds__(256) void k_micro(
    const float* __restrict__ x, const float* __restrict__ W1,
    const float* __restrict__ b1, const float* __restrict__ W2,
    const float* __restrict__ b2, unsigned* __restrict__ h16)
{
    const int tid = threadIdx.x;
    const int r = tid >> 5;                 // row within block (0..7)
    const int p = tid & 31;                 // channel pair (ch 2p, 2p+1)
    const int row0 = blockIdx.x * 8;

    __shared__ float sx[8][16];
    __shared__ float sh1[8][32];

    if (tid < 128) sx[tid >> 4][tid & 15] = x[(size_t)row0 * 16 + tid];

    // preload W2 column pair into registers (32 x float2)
    float2 w2[32];
    #pragma unroll
    for (int j = 0; j < 32; ++j) w2[j] = *(const float2*)&W2[j * 64 + 2 * p];
    const float2 b2p = *(const float2*)&b2[2 * p];
    __syncthreads();

    {   // layer1: 256 thr = 8 rows x 32 cols
        const int rr = tid >> 5, c = tid & 31;
        float a = b1[c];
        #pragma unroll
        for (int i = 0; i < 16; ++i) a += sx[rr][i] * W1[i * 32 + c];
        sh1[rr][c] = fmaxf(a, 0.f);
    }
    __syncthreads();

    {   // layer2: each thread computes 2 channels, packs to f16x2
        float a0 = b2p.x, a1 = b2p.y;
        #pragma unroll
        for (int j = 0; j < 32; ++j) {
            float v = sh1[r][j];
            a0 += v * w2[j].x;
            a1 += v * w2[j].y;
        }
        __half2 hp = __floats2half2_rn(fmaxf(a0, 0.f), fmaxf(a1, 0.f));
        h16[(size_t)(row0 + r) * 32 + p] = *(unsigned*)&hp;
    }
}

// grid 512 (XCD-swizzled), 512 threads = 8 waves.
__global__ __launch_bounds__(512, 4) void k_agg_part(
    const unsigned* __restrict__ h16,  // [B][512][32] f16x2
    const float* __restrict__ tree,    // [128][512]
    const float* __restrict__ W3, const float* __restrict__ b3,
    const float* __restrict__ W4, float* __restrict__ part)
{
    const int id   = blockIdx.x;          // 0..511
    const int b    = (id & 7) * 4 + ((id >> 3) & 3);
    const int ng   = id >> 5;             // 0..15 (nodes ng*8 .. ng*8+7)
    const int tid  = threadIdx.x;
    const int w    = tid >> 6;            // wave 0..7
    const int lane = tid & 63;
    const int half = lane >> 5;           // which of 2 leaves per iter
    const int p    = lane & 31;           // channel pair

    __shared__ unsigned smask[512];       // per-leaf 8-bit node mask
    __shared__ float sred[8][8][64];      // cross-wave max reduce
    __shared__ float sagg[8][64];
    __shared__ float sm[128];
    __shared__ float spart[8][64];

    // ---- per-leaf masks (thread owns leaf tid; coalesced; no atomics) ----
    {
        unsigned bits = 0;
        const float* tp = tree + (size_t)(ng * 8) * 512 + tid;
        #pragma unroll
        for (int n = 0; n < 8; ++n)
            if (tp[(size_t)n * 512] > 0.5f) bits |= (1u << n);
        smask[tid] = bits;
    }
    __syncthreads();

    // ---- packed max-aggregation: wave w owns leaves w*64..w*64+63 ----
    unsigned acc[8];
    #pragma unroll
    for (int n = 0; n < 8; ++n) acc[n] = 0u;        // +0,+0 in f16; h>=0 exact

    const unsigned* hb = h16 + (size_t)b * 16384 + (size_t)(w * 64 + half) * 32 + p;
    const unsigned* mp = &smask[w * 64 + half];
    #pragma unroll 8
    for (int j = 0; j < 32; ++j) {
        unsigned hv  = hb[(size_t)(2 * j) * 32];    // 2 f16 ch, coalesced
        unsigned msk = mp[2 * j];                   // LDS broadcast (2 addr)
        #pragma unroll
        for (int n = 0; n < 8; ++n) {
            int sel = (int)(msk << (31 - n)) >> 31; // bfe: 0 / ~0
            acc[n] = pk_max_f16(acc[n], hv & (unsigned)sel);
        }
    }
    // combine the two half-wave leaf groups
    #pragma unroll
    for (int n = 0; n < 8; ++n) {
        int bi = __shfl_xor((int)acc[n], 32);
        acc[n] = pk_max_f16(acc[n], (unsigned)bi);
    }
    if (half == 0) {
        #pragma unroll
        for (int n = 0; n < 8; ++n) {
            __half2 hh = *(__half2*)&acc[n];
            float2 v = make_float2(__low2float(hh), __high2float(hh));
            *(float2*)&sred[w][n][2 * p] = v;
        }
    }
    __syncthreads();

    {   // combine 8 waves: tid covers (n=tid>>6, c=tid&63)
        const int n = tid >> 6, c = tid & 63;
        float v = sred[0][n][c];
        #pragma unroll
        for (int ww = 1; ww < 8; ++ww) v = fmaxf(v, sred[ww][n][c]);
        sagg[n][c] = v;
    }
    __syncthreads();

    // ---- f_macro: m[n][jj] = relu(b3 + sum_c h_agg*W3) ----
    if (tid < 128) {
        int n = tid >> 4, jj = tid & 15;
        float a = b3[jj];
        #pragma unroll
        for (int c2 = 0; c2 < 64; ++c2)
            a += sagg[n][c2] * W3[c2 * 16 + jj];
        sm[tid] = fmaxf(a, 0.f);
    }
    __syncthreads();

    // ---- W4 slice: part[b][ng][o] = sum_{k in ng*128..+128} m[k]*W4[k][o]
    {
        float a = 0.f;
        const float* w4p = W4 + (size_t)(ng * 128 + w * 16) * 64 + lane;
        #pragma unroll
        for (int k2 = 0; k2 < 16; ++k2)
            a += sm[w * 16 + k2] * w4p[(size_t)k2 * 64];
        spart[w][lane] = a;
    }
    __syncthreads();
    if (tid < 64) {
        float v = 0.f;
        #pragma unroll
        for (int ww = 0; ww < 8; ++ww) v += spart[ww][tid];
        part[((size_t)b * 16 + ng) * 64 + tid] = v;
    }
}

// Combine 16 partials + bias + ReLU -> y; BatchNorm (batch stats over B=32);
// final linear (64->10). One block, 1024 threads.
__global__ __launch_bounds__(1024) void k_bn_out(
    const float* __restrict__ part, const float* __restrict__ b4,
    const float* __restrict__ gamma, const float* __restrict__ beta,
    const float* __restrict__ W5, const float* __restrict__ b5,
    float* __restrict__ out)
{
    const int tid = threadIdx.x;
    __shared__ float sy[32 * 64];
    __shared__ float smean[64], sscale[64], sbeta[64];

    #pragma unroll
    for (int idx = tid; idx < 2048; idx += 1024) {
        int b = idx >> 6, o = idx & 63;
        float v = b4[o];
        #pragma unroll
        for (int s = 0; s < 16; ++s) v += part[((size_t)b * 16 + s) * 64 + o];
        sy[idx] = fmaxf(v, 0.f);
    }
    __syncthreads();
    if (tid < 64) {
        float s1 = 0.f, s2 = 0.f;
        #pragma unroll
        for (int b = 0; b < 32; ++b) {
            float v = sy[b * 64 + tid];
            s1 += v; s2 += v * v;
        }
        float mean = s1 * (1.f / 32.f);
        float var  = s2 * (1.f / 32.f) - mean * mean;   // biased, torch BN
        smean[tid]  = mean;
        sscale[tid] = gamma[tid] * rsqrtf(var + 1e-5f);
        sbeta[tid]  = beta[tid];
    }
    __syncthreads();
    if (tid < 320) {
        int b = tid / 10, q = tid % 10;
        float acc = b5[q];
        #pragma unroll
        for (int o = 0; o < 64; ++o)
            acc += ((sy[b * 64 + o] - smean[o]) * sscale[o] + sbeta[o])
                   * W5[o * 10 + q];
        out[b * 10 + q] = acc;
    }
}

extern "C" void kernel_launch(void* const* d_in, const int* in_sizes, int n_in,
                              void* d_out, int out_size, void* d_ws, size_t ws_size,
                              hipStream_t stream) {
    const float* x     = (const float*)d_in[0];
    const float* tree  = (const float*)d_in[1];
    const float* W1    = (const float*)d_in[2];
    const float* b1    = (const float*)d_in[3];
    const float* W2    = (const float*)d_in[4];
    const float* b2    = (const float*)d_in[5];
    const float* W3    = (const float*)d_in[6];
    const float* b3    = (const float*)d_in[7];
    const float* W4    = (const float*)d_in[8];
    const float* b4    = (const float*)d_in[9];
    const float* gamma = (const float*)d_in[10];
    const float* beta  = (const float*)d_in[11];
    const float* W5    = (const float*)d_in[12];
    const float* b5    = (const float*)d_in[13];
    float* out = (float*)d_out;

    unsigned* h16  = (unsigned*)d_ws;            // 16384*32 u32 = 2 MB
    float*    part = (float*)(h16 + 16384 * 32); // 32*16*64 f32 = 128 KB

    k_micro   <<<2048, 256, 0, stream>>>(x, W1, b1, W2, b2, h16);
    k_agg_part<<<512,  512, 0, stream>>>(h16, tree, W3, b3, W4, part);
    k_bn_out  <<<1,   1024, 0, stream>>>(part, b4, gamma, beta, W5, b5, out);
}